// Round 4
// baseline (67.224 us; speedup 1.0000x reference)
//
#include <hip/hip_runtime.h>

// Problem constants (from reference):
#define BB 8
#define NN 32768
#define CC 4
#define MM 11          // memory length (FIR taps)
#define KK 55          // D*M
#define THREADS 256
#define WAVES (THREADS / 64)
#define HALO (MM - 1)              // 10
#define WTILE (64 + HALO)          // 74 samples per wave tile

// out[b,c,n] = sum_{j=0..10} z[n-10+j] * ( sum_d W[c, d*11+j] * |z[n-10+j]|^d )
// z[t] = x[b,t,c,0] + i x[b,t,c,1], zero for t<0.
//
// Round-4 design: wave-synchronous tiles, NO __syncthreads. Each wave stages
// its own 74 samples (64 + 10-halo via lanes 0..9) into a private LDS region,
// fences with s_waitcnt lgkmcnt(0) (lockstep wave, in-order DS pipe), then
// consumes. Removes the block-wide barrier drain: a wave only waits on its own
// 2 global loads, hidden across 32 waves/CU. Halo duplication (74/64) is
// L2-absorbed. blockIdx.z = channel pair (weights stay SGPR-uniform).

__global__ __launch_bounds__(THREADS, 8)
void gmp_kernel(const float* __restrict__ x,
                const float* __restrict__ W,
                float* __restrict__ out) {
    __shared__ float4 zs[WAVES][WTILE];    // (re0, im0, re1, im1) per sample
    __shared__ float2 as2[WAVES][WTILE];   // |z| for the two channels

    const int tid  = threadIdx.x;
    const int wid  = tid >> 6;
    const int lane = tid & 63;
    const int b  = blockIdx.y;
    const int h  = blockIdx.z;                       // channels 2h, 2h+1
    const int n0 = blockIdx.x * THREADS + wid * 64;  // this wave's first output
    const int n  = n0 + lane;

    const float4* xg = (const float4*)x + (size_t)b * NN * 2;

    // Main sample t = n -> slot 10+lane.
    float4 v = xg[2 * n + h];
    // Halo: lanes 0..9 load t = n0-10+lane -> slot lane (zero-fill t<0).
    float4 vh = make_float4(0.f, 0.f, 0.f, 0.f);
    const int th = n0 - HALO + lane;
    if (lane < HALO && th >= 0) vh = xg[2 * th + h];

    float2 a;
    a.x = sqrtf(fmaf(v.x, v.x, v.y * v.y));
    a.y = sqrtf(fmaf(v.z, v.z, v.w * v.w));
    zs[wid][HALO + lane] = v;
    as2[wid][HALO + lane] = a;
    if (lane < HALO) {
        float2 ah;
        ah.x = sqrtf(fmaf(vh.x, vh.x, vh.y * vh.y));
        ah.y = sqrtf(fmaf(vh.z, vh.z, vh.w * vh.w));
        zs[wid][lane] = vh;
        as2[wid][lane] = ah;
    }
    // Wave-synchronous fence: drain DS writes, block compiler reordering.
    asm volatile("s_waitcnt lgkmcnt(0)" ::: "memory");

    // Weight rows for this pair — wave-uniform -> scalar loads.
    const float* W0 = W + (2 * h) * KK;
    const float* W1 = W + (2 * h + 1) * KK;

    float ar0 = 0.f, ai0 = 0.f, ar1 = 0.f, ai1 = 0.f;

    #pragma unroll
    for (int j = 0; j < MM; j++) {
        const float4 z = zs[wid][lane + j];
        const float2 am = as2[wid][lane + j];
        {
            float p = W0[4 * MM + j];
            p = fmaf(p, am.x, W0[3 * MM + j]);
            p = fmaf(p, am.x, W0[2 * MM + j]);
            p = fmaf(p, am.x, W0[1 * MM + j]);
            p = fmaf(p, am.x, W0[0 * MM + j]);
            ar0 = fmaf(z.x, p, ar0);
            ai0 = fmaf(z.y, p, ai0);
        }
        {
            float p = W1[4 * MM + j];
            p = fmaf(p, am.y, W1[3 * MM + j]);
            p = fmaf(p, am.y, W1[2 * MM + j]);
            p = fmaf(p, am.y, W1[1 * MM + j]);
            p = fmaf(p, am.y, W1[0 * MM + j]);
            ar1 = fmaf(z.z, p, ar1);
            ai1 = fmaf(z.w, p, ai1);
        }
    }

    // out[b,n,c,{re,im}]: channels 2h,2h+1 -> 16 contiguous bytes.
    float4* og = (float4*)out + ((size_t)(b * NN + n) * 2 + h);
    *og = make_float4(ar0, ai0, ar1, ai1);
}

extern "C" void kernel_launch(void* const* d_in, const int* in_sizes, int n_in,
                              void* d_out, int out_size, void* d_ws, size_t ws_size,
                              hipStream_t stream) {
    const float* x = (const float*)d_in[0];   // [B,N,C,2] fp32
    const float* W = (const float*)d_in[1];   // [C,K] fp32
    float* out = (float*)d_out;               // [B,N,C,2] fp32

    dim3 grid(NN / THREADS, BB, 2);           // 128 x 8 x 2 = 2048 blocks
    gmp_kernel<<<grid, THREADS, 0, stream>>>(x, W, out);
}